// Round 4
// baseline (312.848 us; speedup 1.0000x reference)
//
#include <hip/hip_runtime.h>

// YOLO loss, MI355X. B=16, GH=GW=64, NA=3, NC=80, T=100, net=1024.
// y_pred/y_true: contiguous (196608, 85) fp32. true_boxes: (16,100,4) fp32.
// out: 16 fp32 per-batch loss.
//
// R9: attack the structure-invariant cost — serial chains + occupancy.
//  Evidence: R5 (no staging, atomics) 315.9 / R7 (full LDS streaming)
//  318.0 / R8 (no atomics) 310.0 — ALL within the +-3% noise band. Load
//  path and reduction tail are NOT the bottleneck. Common to all three:
//  per-thread serial chains (21-exp class scan, 25-iter dependent
//  rcp->fmax IoU chain, ~20 dependent shuffles) at ~3 waves/SIMD
//  occupancy (LDS 46.7KB or staged-granule VGPR pressure). Theory:
//  latency-chain-bound at low occupancy -> halve chains, double waves.
//  - 8 threads/row (o=tid&7): classes via granules j=2+o+8k (k<3, j<=20),
//    head classes c0..c2 on o==7 (from g1/h1), tail c79 scalar on o==3.
//    IoU boxes k=o+8m (12-13 each). Merges: shfl_xor 1,2,4.
//  - NO LDS slab (R5/R7 equivalence proved staging neutral; L2 absorbs
//    340-B-row granule reads). LDS = sbox(1.6KB)+swsum only -> occupancy
//    VGPR-limited, in-loop granule consumption keeps ~55 VGPR -> 6-8
//    waves/SIMD (2-2.7x R7/R8).
//  - Tail: per-block plain store to d_ws + 16-block reducer (R8, kept).
//  - no-max logsumexp (inputs ~N(0,1), fp32-safe); first-max tie-break.

#define NT 100
#define CPB 12288            // rows per batch
#define NTOT 196608
#define ROWS_PER_BLOCK 32    // 8 threads/row, 256 threads = 4 waves
#define NBLOCKS (NTOT / ROWS_PER_BLOCK)   // 6144
#define BLOCKS_PER_B (NBLOCKS / 16)       // 384

typedef float f4 __attribute__((ext_vector_type(4)));
typedef f4 f4a __attribute__((aligned(4)));   // rows are 340 B: 4-B aligned

__device__ __forceinline__ float frcp(float x) { return __builtin_amdgcn_rcpf(x); }
__device__ __forceinline__ float fsig(float x) { return frcp(1.f + __expf(-x)); }

__global__ __launch_bounds__(256) void yolo_loss_kernel(
    const float* __restrict__ y_pred,
    const float* __restrict__ y_true,
    const float* __restrict__ true_boxes,
    float* __restrict__ ws)
{
    __shared__ f4 sbox[NT];       // (minx,miny,maxx,maxy), batch-uniform
    __shared__ float swsum[4];

    const int tid = threadIdx.x;
    const int o   = tid & 7;                     // worker within row
    const int row = blockIdx.x * ROWS_PER_BLOCK + (tid >> 3);
    const int b   = row / CPB;                   // block-uniform (32 | 12288)

    if (tid < NT) {
        const f4 tb = *(const f4*)(true_boxes + (size_t)b * NT * 4 + tid * 4);
        const float tx = tb.x * (1.f / 64.f),   ty = tb.y * (1.f / 64.f);
        const float tw = tb.z * (1.f / 1024.f), th = tb.w * (1.f / 1024.f);
        f4 r;
        r.x = tx - 0.5f * tw; r.y = ty - 0.5f * th;
        r.z = tx + 0.5f * tw; r.w = ty + 0.5f * th;
        sbox[tid] = r;
    }
    __syncthreads();

    const int rem = row % CPB;
    const int gy  = rem / 192;
    const int rr  = rem - gy * 192;
    const int gx  = rr / 3;
    const int a   = rr - gx * 3;
    const float aw = (a == 0) ? 116.f : ((a == 1) ? 156.f : 373.f);
    const float ah = (a == 0) ? 90.f  : ((a == 1) ? 198.f : 326.f);

    const float* p = y_pred + (size_t)row * 85;
    const float* t = y_true + (size_t)row * 85;

    // head granules (shared by the 8 lanes of a row; line-overlapped)
    const f4 g0 = *(const f4a*)p;            // p0..p3
    const f4 g1 = *(const f4a*)(p + 4);      // p4, c0..c2
    const f4 h0 = *(const f4a*)t;            // t0..t3
    const f4 h1 = *(const f4a*)(t + 4);      // om, tc0..tc2

    const float p4v = g1.x, om = h1.x;

    // ---- class pass: granules j = 2+o+8k (j<=20), head on o==7, tail on o==3 ----
    float ssum = 0.f, tmax = -1e30f, psel = 0.f;
    int jm = 1 << 20;
    if (o == 7) {   // classes 0..2 from granule 1 (lowest indices first)
#pragma unroll
        for (int e = 1; e < 4; ++e) {
            const float pv = g1[e], tv = h1[e];
            ssum += __expf(pv);
            const bool g = tv > tmax;
            tmax = g ? tv : tmax; psel = g ? pv : psel; jm = g ? (e - 1) : jm;
        }
    }
#pragma unroll
    for (int k = 0; k < 3; ++k) {
        const int j = 2 + o + 8 * k;
        if (j <= 20) {               // j==21 (o==3,k==2) handled as scalar tail
            const f4 pv4 = *(const f4a*)(p + 4 * j);
            const f4 tv4 = *(const f4a*)(t + 4 * j);
#pragma unroll
            for (int e = 0; e < 4; ++e) {
                const float pv = pv4[e], tv = tv4[e];
                ssum += __expf(pv);
                const bool g = tv > tmax;
                tmax = g ? tv : tmax; psel = g ? pv : psel;
                jm = g ? (4 * j + e - 5) : jm;
            }
        }
    }
    if (o == 3) {   // class 79 (row float 84; in-bounds for every row)
        const float pv = p[84], tv = t[84];
        ssum += __expf(pv);
        const bool g = tv > tmax;
        tmax = g ? tv : tmax; psel = g ? pv : psel; jm = g ? 79 : jm;
    }
    // octet merge: sum; argmax with first-max (lowest index) tie-break
#pragma unroll
    for (int off = 1; off < 8; off <<= 1) {
        ssum += __shfl_xor(ssum, off, 64);
        const float otm = __shfl_xor(tmax, off, 64);
        const float ops = __shfl_xor(psel, off, 64);
        const int   ojm = __shfl_xor(jm, off, 64);
        const bool adopt = (otm > tmax) || (otm == tmax && ojm < jm);
        tmax = adopt ? otm : tmax; psel = adopt ? ops : psel; jm = adopt ? ojm : jm;
    }
    const float ce = __logf(ssum) - psel;    // -log_softmax at true class

    // ---- pred box + IoU vs 100 true boxes (12-13 per thread) ----
    const float predx = (float)gx + fsig(g0.x);
    const float predy = (float)gy + fsig(g0.y);
    const float conf  = fsig(p4v);
    const float pw  = __expf(g0.z) * aw * (1.f / 1024.f);
    const float phh = __expf(g0.w) * ah * (1.f / 1024.f);
    const float parea = pw * phh;
    const float px = predx * (1.f / 64.f), py = predy * (1.f / 64.f);
    const float pminx = px - 0.5f * pw,  pmaxx = px + 0.5f * pw;
    const float pminy = py - 0.5f * phh, pmaxy = py + 0.5f * phh;

    float best = 0.f;
#pragma unroll
    for (int m = 0; m < 13; ++m) {           // sbox[o+8m]: disjoint banks, broadcast
        const int kk = o + 8 * m;
        if (kk < NT) {
            const f4 bx = sbox[kk];
            float iw = fminf(pmaxx, bx.z) - fmaxf(pminx, bx.x);
            float ih = fminf(pmaxy, bx.w) - fmaxf(pminy, bx.y);
            iw = fmaxf(iw, 0.f); ih = fmaxf(ih, 0.f);
            const float inter = iw * ih;
            const float tarea = (bx.z - bx.x) * (bx.w - bx.y);
            best = fmaxf(best, inter * frcp(parea + tarea - inter));
        }
    }
#pragma unroll
    for (int off = 1; off < 8; off <<= 1)
        best = fmaxf(best, __shfl_xor(best, off, 64));
    const float ignore = (best > 0.5f) ? 1.f : 0.f;

    // ---- deltas (all lanes compute; only o==0 contributes) ----
    const float wsx = __expf(h0.z) * aw * (1.f / 1024.f);
    const float wsy = __expf(h0.w) * ah * (1.f / 1024.f);
    const float wsc = 2.f - wsx * wsy;
    const float omws = om * wsc;
    const float dx = omws * (h0.x - predx);
    const float dy = omws * (h0.y - predy);
    const float dw = omws * (h0.z - g0.z);
    const float dh = omws * (h0.w - g0.w);
    float dc = -conf + om * (1.f - conf) * 5.f;
    dc *= (1.f - (1.f - om) * ignore);
    const float dcl = om * ce;

    float val = dx * dx + dy * dy + dw * dw + dh * dh + dc * dc + dcl * dcl;
    val = (o == 0) ? val : 0.f;

    // wave reduce -> LDS -> one plain store per block
#pragma unroll
    for (int off = 32; off > 0; off >>= 1) val += __shfl_down(val, off, 64);
    if ((tid & 63) == 0) swsum[tid >> 6] = val;
    __syncthreads();
    if (tid == 0) ws[blockIdx.x] = swsum[0] + swsum[1] + swsum[2] + swsum[3];
}

// Stage 2: 16 blocks x 1 wave; sum 384 partials per batch, write out directly.
__global__ __launch_bounds__(64) void yolo_reduce_kernel(
    const float* __restrict__ ws, float* __restrict__ out)
{
    const int l = threadIdx.x;
    const float* p = ws + blockIdx.x * BLOCKS_PER_B;
    float v = 0.f;
#pragma unroll
    for (int i = 0; i < BLOCKS_PER_B / 64; ++i) v += p[l + 64 * i];
#pragma unroll
    for (int off = 32; off > 0; off >>= 1) v += __shfl_down(v, off, 64);
    if (l == 0) out[blockIdx.x] = v;
}

extern "C" void kernel_launch(void* const* d_in, const int* in_sizes, int n_in,
                              void* d_out, int out_size, void* d_ws, size_t ws_size,
                              hipStream_t stream) {
    // inputs: [0]=input_image (shape-only, never read), [1]=y_pred, [2]=y_true, [3]=true_boxes
    const float* y_pred     = (const float*)d_in[1];
    const float* y_true     = (const float*)d_in[2];
    const float* true_boxes = (const float*)d_in[3];
    float* ws  = (float*)d_ws;
    float* out = (float*)d_out;

    yolo_loss_kernel<<<NBLOCKS, 256, 0, stream>>>(y_pred, y_true, true_boxes, ws);
    yolo_reduce_kernel<<<16, 64, 0, stream>>>(ws, out);
}